// Round 5
// baseline (1163.093 us; speedup 1.0000x reference)
//
#include <hip/hip_runtime.h>

typedef __attribute__((ext_vector_type(8))) short short8;
typedef __attribute__((ext_vector_type(4))) float f32x4;

__device__ __forceinline__ ushort f2bf(float f){
    union { float f; unsigned u; } v; v.f = f;
    unsigned r = (v.u + 0x7fffu + ((v.u >> 16) & 1u)) >> 16;
    return (ushort)r;
}
__device__ __forceinline__ float bf2f(ushort u){
    union { unsigned u; float f; } v; v.u = ((unsigned)u) << 16;
    return v.f;
}

// ---------------- Layer 1: Cin=1 -> 40 real (stored 64, pad zero), direct fp32 ----------
__global__ __launch_bounds__(256) void conv_l1(
    const float* __restrict__ x, const float* __restrict__ w,
    const float* __restrict__ bias, ushort* __restrict__ out)
{
    __shared__ float xs[2916];     // [3][3][18][18] padded neighborhood
    __shared__ float wsh[3240];    // [40][81]
    const int tid = threadIdx.x;
    const int bx = blockIdx.x;
    const int d2 = bx & 15, d1 = (bx >> 4) & 15, b = bx >> 8;
    const float* xb = x + (size_t)b * 65536;

    for (int i = tid; i < 2916; i += 256){
        int i4 = i % 18; int r1 = i / 18; int i3 = r1 % 18;
        int r2 = r1 / 18; int a2 = r2 % 3; int a1 = r2 / 3;
        int e1 = d1 + a1 - 1, e2 = d2 + a2 - 1, e3 = i3 - 1, e4 = i4 - 1;
        float v = 0.f;
        if ((unsigned)e1 < 16u && (unsigned)e2 < 16u && (unsigned)e3 < 16u && (unsigned)e4 < 16u)
            v = xb[((e1 * 16 + e2) * 16 + e3) * 16 + e4];
        xs[i] = v;
    }
    for (int i = tid; i < 3240; i += 256) wsh[i] = w[i];
    __syncthreads();

    const int d3 = tid >> 4, d4 = tid & 15;
    float acc[40];
    #pragma unroll
    for (int c = 0; c < 40; ++c) acc[c] = 0.f;

    for (int t1 = 0; t1 < 3; ++t1)
    for (int t2 = 0; t2 < 3; ++t2)
    for (int t3 = 0; t3 < 3; ++t3)
    #pragma unroll
    for (int t4 = 0; t4 < 3; ++t4){
        float xv = xs[((t1 * 3 + t2) * 18 + d3 + t3) * 18 + d4 + t4];
        int tap = ((t1 * 3 + t2) * 3 + t3) * 3 + t4;
        #pragma unroll
        for (int c = 0; c < 40; ++c) acc[c] += wsh[c * 81 + tap] * xv;
    }

    ushort* ob = out + ((size_t)bx * 256 + tid) * 64;
    #pragma unroll
    for (int c = 0; c < 40; ++c){
        float v = acc[c] + bias[c]; v = v > 0.f ? v : 0.f;
        ob[c] = f2bf(v);
    }
    #pragma unroll
    for (int c = 40; c < 64; ++c) ob[c] = 0;
}

// ---------------- Layer 6: 40 real (stored 64) -> Cout=1, direct fp32 -------------------
__global__ __launch_bounds__(256) void conv_l6(
    const ushort* __restrict__ in, const float* __restrict__ w,
    const float* __restrict__ bias, float* __restrict__ out)
{
    __shared__ float wsh[3240];    // [ci=40][81]
    const int tid = threadIdx.x;
    const int bx = blockIdx.x;
    const int d2 = bx & 15, d1 = (bx >> 4) & 15, b = bx >> 8;
    for (int i = tid; i < 3240; i += 256) wsh[i] = w[i];
    __syncthreads();

    const int d3 = tid >> 4, d4 = tid & 15;
    const ushort* inb = in + (size_t)b * 65536 * 64;
    float acc = 0.f;
    for (int t1 = 0; t1 < 3; ++t1){
        int e1 = d1 + t1 - 1; if ((unsigned)e1 >= 16u) continue;
        for (int t2 = 0; t2 < 3; ++t2){
            int e2 = d2 + t2 - 1; if ((unsigned)e2 >= 16u) continue;
            for (int t3 = 0; t3 < 3; ++t3){
                int e3 = d3 + t3 - 1; if ((unsigned)e3 >= 16u) continue;
                for (int t4 = 0; t4 < 3; ++t4){
                    int e4 = d4 + t4 - 1; if ((unsigned)e4 >= 16u) continue;
                    const ushort* p = inb + (size_t)(((e1 * 16 + e2) * 16 + e3) * 16 + e4) * 64;
                    int tap = ((t1 * 3 + t2) * 3 + t3) * 3 + t4;
                    #pragma unroll
                    for (int c8 = 0; c8 < 5; ++c8){
                        short8 v = *(const short8*)(p + c8 * 8);
                        #pragma unroll
                        for (int j = 0; j < 8; ++j)
                            acc += bf2f((ushort)v[j]) * wsh[(c8 * 8 + j) * 81 + tap];
                    }
                }
            }
        }
    }
    float v = acc + bias[0]; v = v > 0.f ? v : 0.f;
    out[(size_t)bx * 256 + tid] = v;
}

// ---------------- Weight repack: [co][ci][81] fp32 -> [81][ci/8][co][8] bf16 ------------
__global__ void repack_w(const float* __restrict__ w, ushort* __restrict__ wp,
                         int cin, int cout, int cin_s, int cout_c)
{
    const int total = 81 * cin_s * cout_c;
    for (int i = blockIdx.x * blockDim.x + threadIdx.x; i < total; i += gridDim.x * blockDim.x){
        int j = i & 7;
        int rest = i >> 3;
        int co = rest % cout_c;
        int rest2 = rest / cout_c;
        int ci_hi = rest2 % (cin_s >> 3);
        int t = rest2 / (cin_s >> 3);
        int ci = ci_hi * 8 + j;
        float v = (ci < cin && co < cout) ? w[((size_t)co * cin + ci) * 81 + t] : 0.f;
        wp[i] = f2bf(v);
    }
}

// ---------------- MFMA implicit-GEMM conv layer, 2-phase pipelined ----------------------
// in : [b][d1][d2][d3][d4][CIN_S]  bf16
// wp : [81][ci/8][COUT_C][8]       bf16 (B-fragment native)
// out: [b][d1][d2][d3][d4][COUT_C] bf16
// A: staged once per (t1,t2) plane, full channels, odd-slot row stride (bank-conflict-free),
//    loads issued at tap 8 of previous plane (latency hidden under MFMA).
// B: staged per tap [CIN_S][COUT_C], double-buffered, loads at tap start / ds_write at end.
// One barrier per tap (~60 MFMA/barrier on L3/L4).
template<int CIN_S, int COUT_C, int MINW>
__global__ __launch_bounds__(512, MINW) void conv_mfma(
    const ushort* __restrict__ in, const ushort* __restrict__ wp,
    const float* __restrict__ bias, int cout_real, ushort* __restrict__ out)
{
    constexpr int AP  = CIN_S + 8;            // row stride in shorts; AP/8 is odd
    constexpr int KC  = CIN_S / 32;           // K chunks per tap
    constexpr int NT  = COUT_C / 32;          // N tiles per wave (2 N-waves)
    constexpr int NLA = CIN_S / 16;           // A short8 loads per thread
    constexpr int NB8 = CIN_S * COUT_C / 8;   // B short8 chunks per tap
    constexpr int NLB = (NB8 + 511) / 512;

    __shared__ __attribute__((aligned(16))) ushort As[256 * AP];
    __shared__ __attribute__((aligned(16))) ushort Bs[2][CIN_S * COUT_C];

    const int tid = threadIdx.x;
    const int lane = tid & 63;
    const int w = tid >> 6;
    const int wm = w >> 1;          // 0..3 (d3 group)
    const int wn = w & 1;           // N half
    const int r = lane & 15;        // A-row (=d4) / B-col / D-col
    const int g = lane >> 4;        // k-group / D row-group

    // XCD-aware chunked swizzle (grid=512, 8 XCDs, 64 blocks/XCD-chunk)
    const int p0 = blockIdx.x;
    const int bx = (p0 & 7) * 64 + (p0 >> 3);
    const int d2 = bx & 15, d1 = (bx >> 4) & 15, b = bx >> 8;

    const ushort* inb = in + (size_t)b * 65536 * CIN_S;
    const int co0 = wn * NT * 16;

    f32x4 acc[4][NT];
    #pragma unroll
    for (int f = 0; f < 4; ++f)
        #pragma unroll
        for (int n = 0; n < NT; ++n)
            acc[f][n] = (f32x4){0.f, 0.f, 0.f, 0.f};

    short8 areg[NLA];
    short8 breg[NLB];

    auto loadA = [&](int e1, int e2){
        const ushort* src = inb + ((size_t)(e1 * 16 + e2) * 256) * CIN_S;
        #pragma unroll
        for (int k = 0; k < NLA; ++k)
            areg[k] = *(const short8*)(src + (size_t)(tid + k * 512) * 8);
    };
    auto writeA = [&](){
        #pragma unroll
        for (int k = 0; k < NLA; ++k){
            const int i = tid + k * 512;
            const int pos = i / (CIN_S / 8), k8 = i % (CIN_S / 8);
            *(short8*)(As + pos * AP + k8 * 8) = areg[k];
        }
    };
    auto loadB = [&](int t){
        const short8* src = (const short8*)(wp + (size_t)t * (CIN_S * COUT_C));
        #pragma unroll
        for (int k = 0; k < NLB; ++k){
            const int i = tid + k * 512;
            if (i < NB8) breg[k] = src[i];
        }
    };
    auto writeB = [&](int s){
        #pragma unroll
        for (int k = 0; k < NLB; ++k){
            const int i = tid + k * 512;
            if (i < NB8) *(((short8*)Bs[s]) + i) = breg[k];
        }
    };

    // prologue: B(0) staged, A(gg=0) loads in flight
    loadB(0); writeB(0);
    if ((unsigned)(d1 - 1) < 16u && (unsigned)(d2 - 1) < 16u) loadA(d1 - 1, d2 - 1);

    int cur = 0;
    for (int t = 0; t < 81; ++t){
        const int gg = t / 9, tt = t - gg * 9;
        const int t1 = gg / 3, t2 = gg - t1 * 3;
        const int e1 = d1 + t1 - 1, e2 = d2 + t2 - 1;
        const bool gv = ((unsigned)e1 < 16u) && ((unsigned)e2 < 16u);   // block-uniform

        if (tt == 0 && gv){
            __syncthreads();          // all reads of old A done
            writeA();
            __syncthreads();          // new A visible
        }

        if (t < 80) loadB(t + 1);     // B prefetch (global -> regs), hidden under MFMA

        // A prefetch for next plane, issued early so latency hides under this tap
        if (tt == 8 && t < 80){
            const int ng = gg + 1;
            const int n1 = ng / 3, n2 = ng - n1 * 3;
            const int f1 = d1 + n1 - 1, f2 = d2 + n2 - 1;
            if ((unsigned)f1 < 16u && (unsigned)f2 < 16u) loadA(f1, f2);
        }

        if (gv){
            const int t3 = tt / 3, t4 = tt - t3 * 3;
            const int e4 = r + t4 - 1;
            const bool v4 = (unsigned)e4 < 16u;
            __builtin_amdgcn_s_setprio(1);
            #pragma unroll
            for (int c = 0; c < KC; ++c){
                short8 bfr[NT];
                #pragma unroll
                for (int n = 0; n < NT; ++n)
                    bfr[n] = *(const short8*)(Bs[cur] + ((c * 4 + g) * COUT_C + co0 + n * 16 + r) * 8);
                #pragma unroll
                for (int f = 0; f < 4; ++f){
                    const int e3 = wm * 4 + f + t3 - 1;
                    if ((unsigned)e3 < 16u){
                        short8 af = {0, 0, 0, 0, 0, 0, 0, 0};
                        if (v4)
                            af = *(const short8*)(As + (e3 * 16 + e4) * AP + c * 32 + g * 8);
                        #pragma unroll
                        for (int n = 0; n < NT; ++n)
                            acc[f][n] = __builtin_amdgcn_mfma_f32_16x16x32_bf16(af, bfr[n], acc[f][n], 0, 0, 0);
                    }
                }
            }
            __builtin_amdgcn_s_setprio(0);
        }

        if (t < 80) writeB(cur ^ 1);
        __syncthreads();
        cur ^= 1;
    }

    // epilogue: bias + ReLU + bf16 store
    float bv[NT];
    #pragma unroll
    for (int n = 0; n < NT; ++n){
        int co = co0 + n * 16 + r;
        bv[n] = (co < cout_real) ? bias[co] : 0.f;
    }
    ushort* ob = out + (size_t)bx * 256 * COUT_C;
    #pragma unroll
    for (int f = 0; f < 4; ++f){
        const int d3 = wm * 4 + f;
        #pragma unroll
        for (int n = 0; n < NT; ++n){
            const int co = co0 + n * 16 + r;
            #pragma unroll
            for (int j = 0; j < 4; ++j){
                const int d4 = g * 4 + j;
                float v = acc[f][n][j] + bv[n];
                v = v > 0.f ? v : 0.f;
                ob[(size_t)(d3 * 16 + d4) * COUT_C + co] = f2bf(v);
            }
        }
    }
}

extern "C" void kernel_launch(void* const* d_in, const int* in_sizes, int n_in,
                              void* d_out, int out_size, void* d_ws, size_t ws_size,
                              hipStream_t stream) {
    const float* x  = (const float*)d_in[0];
    const float* w1 = (const float*)d_in[1];  const float* b1 = (const float*)d_in[2];
    const float* w2 = (const float*)d_in[3];  const float* b2 = (const float*)d_in[4];
    const float* w3 = (const float*)d_in[5];  const float* b3 = (const float*)d_in[6];
    const float* w4 = (const float*)d_in[7];  const float* b4 = (const float*)d_in[8];
    const float* w5 = (const float*)d_in[9];  const float* b5 = (const float*)d_in[10];
    const float* w6 = (const float*)d_in[11]; const float* b6 = (const float*)d_in[12];

    // workspace layout (bf16 ushorts):
    ushort* bufA = (ushort*)d_ws;                       // [131072][160] : 41.9 MB
    ushort* bufB = bufA + (size_t)131072 * 160;         // [131072][96]  : 25.2 MB
    ushort* wp2  = bufB + (size_t)131072 * 96;          // 81*64*96
    ushort* wp3  = wp2 + (size_t)81 * 64 * 96;          // 81*96*160
    ushort* wp4  = wp3 + (size_t)81 * 96 * 160;         // 81*160*96
    ushort* wp5  = wp4 + (size_t)81 * 160 * 96;         // 81*96*64

    repack_w<<<512, 256, 0, stream>>>(w2, wp2, 40, 80, 64, 96);
    repack_w<<<512, 256, 0, stream>>>(w3, wp3, 80, 160, 96, 160);
    repack_w<<<512, 256, 0, stream>>>(w4, wp4, 160, 80, 160, 96);
    repack_w<<<512, 256, 0, stream>>>(w5, wp5, 80, 40, 96, 64);

    conv_l1<<<512, 256, 0, stream>>>(x, w1, b1, bufA);
    conv_mfma< 64,  96, 4><<<512, 512, 0, stream>>>(bufA, wp2, b2, 80, bufB);
    conv_mfma< 96, 160, 2><<<512, 512, 0, stream>>>(bufB, wp3, b3, 160, bufA);
    conv_mfma<160,  96, 2><<<512, 512, 0, stream>>>(bufA, wp4, b4, 80, bufB);
    conv_mfma< 96,  64, 4><<<512, 512, 0, stream>>>(bufB, wp5, b5, 40, bufA);
    conv_l6<<<512, 256, 0, stream>>>(bufA, w6, b6, (float*)d_out);
}